// Round 11
// baseline (316.416 us; speedup 1.0000x reference)
//
#include <hip/hip_runtime.h>
#include <hip/hip_bf16.h>

#define DEVI __device__ __forceinline__

typedef __attribute__((ext_vector_type(8))) __bf16 bf16x8;
typedef __attribute__((ext_vector_type(4))) __bf16 bf16x4;
typedef __attribute__((ext_vector_type(4))) float f32x4;

using bf16 = __hip_bfloat16;

DEVI float bf2f(bf16 v) { return __bfloat162float(v); }
DEVI bf16 f2bf(float v) { return __float2bfloat16(v); }

// tanh-form GELU; max |diff vs exact| ~3e-3, under bf16 epilogue noise.
DEVI float gelu_fast(float v) {
    float t = v * (2.30220777f + 0.10294322f * v * v);
    float e = __builtin_amdgcn_exp2f(t);
    return v - v * __builtin_amdgcn_rcpf(e + 1.0f);
}

DEVI void async16(void* lds, const void* g) {
    __builtin_amdgcn_global_load_lds(
        (const __attribute__((address_space(1))) void*)g,
        (__attribute__((address_space(3))) void*)lds, 16, 0, 0);
}

// sign of e_i * e_j in 16-dim Cayley-Dickson algebra (index is i^j)
DEVI int cd_sign(int i, int j) {
    int s = 1, n = 16;
    while (n > 1) {
        int h = n >> 1;
        int ih = (i >= h), jh = (j >= h);
        if (!ih && !jh) {
        } else if (!ih && jh) {
            int ni = j - h, nj = i;
            i = ni; j = nj;
        } else if (ih && !jh) {
            if (j != 0) s = -s;
            i = i - h;
        } else {
            int ni = j - h, nj = i - h;
            if (ni == 0) s = -s;
            i = ni; j = nj;
        }
        n = h;
    }
    return s;
}

// ---------------- fused front: ln1 (1024 blk) + prep_A (256) + prep_w (576) --
// v4: LDS union shrunk 69120 -> 39936 B => 4 blocks/CU (16 waves) vs 2 (8).
// r10 budget: front ~85-110 us at ~2 TB/s for 201 MB streaming -- TLP-starved
// (G1).  ln1 tile now bf16 [128][136] (34816 B); LN1 stats computed from the
// fp32 loads IN REGISTERS (per-thread partials -> shfl_xor(32) -> 4 KB LDS
// reduce), so stats precision is unchanged; xt is bit-identical; xn absorbs
// one input-rounding ulp (~0.008, under the passing 0.05-0.09 absmax band).
// prep_A strip-mined to [128][66] fp32 (two 64-col passes, 33792 B).
__global__ __launch_bounds__(256) void k_front(
    const float* __restrict__ x, const float* __restrict__ g,
    const float* __restrict__ bta, const float* __restrict__ sed_w,
    const float* __restrict__ wp, const float* __restrict__ w1,
    const float* __restrict__ w2,
    bf16* __restrict__ xt, bf16* __restrict__ xn, bf16* __restrict__ At,
    bf16* __restrict__ wpT, bf16* __restrict__ w1T, bf16* __restrict__ w2T) {
    __shared__ __align__(16) char fbuf[39936];
    int bid = blockIdx.x;
    int t = threadIdx.x;

    if (bid < 1024) {
        // ---- LN1 + transpose to window-permuted token order ----------------
        bf16 (*tileB)[136] = (bf16(*)[136])fbuf;             // 34816 B
        float* red = (float*)(fbuf + 34816);                 // s[4][128], ss[4][128]
        float* msh = (float*)(fbuf + 38912);                 // mean[128]
        float* rsh = (float*)(fbuf + 39424);                 // rstd[128]
        int b = bid >> 7, r = bid & 127;
        const float* xb = x + ((long)b * 16384 + r) * 128;
        int grp = t >> 5;            // 0..7 channel group
        int c4 = (t & 31) * 4;       // float4 column base
        float s0 = 0, s1 = 0, s2 = 0, s3 = 0;
        float q0 = 0, q1 = 0, q2 = 0, q3 = 0;
#pragma unroll
        for (int it = 0; it < 16; ++it) {
            int ch = it * 8 + grp;
            float4 v = *(const float4*)&xb[(long)ch * 16384 + c4];
            bf16x4 pv;
            pv[0] = (__bf16)v.x; pv[1] = (__bf16)v.y;
            pv[2] = (__bf16)v.z; pv[3] = (__bf16)v.w;
            *(bf16x4*)&tileB[ch][c4] = pv;
            s0 += v.x; q0 += v.x * v.x;
            s1 += v.y; q1 += v.y * v.y;
            s2 += v.z; q2 += v.z * v.z;
            s3 += v.w; q3 += v.w * v.w;
        }
        // combine grp pairs (2w, 2w+1) within each wave
        s0 += __shfl_xor(s0, 32); q0 += __shfl_xor(q0, 32);
        s1 += __shfl_xor(s1, 32); q1 += __shfl_xor(q1, 32);
        s2 += __shfl_xor(s2, 32); q2 += __shfl_xor(q2, 32);
        s3 += __shfl_xor(s3, 32); q3 += __shfl_xor(q3, 32);
        int wv = t >> 6;
        if ((t & 63) < 32) {
            red[wv * 128 + c4 + 0] = s0; red[512 + wv * 128 + c4 + 0] = q0;
            red[wv * 128 + c4 + 1] = s1; red[512 + wv * 128 + c4 + 1] = q1;
            red[wv * 128 + c4 + 2] = s2; red[512 + wv * 128 + c4 + 2] = q2;
            red[wv * 128 + c4 + 3] = s3; red[512 + wv * 128 + c4 + 3] = q3;
        }
        __syncthreads();
        if (t < 128) {
            float S = red[t] + red[128 + t] + red[256 + t] + red[384 + t];
            float SS = red[512 + t] + red[640 + t] + red[768 + t] + red[896 + t];
            float mean = S * (1.f / 128.f);
            float var = SS * (1.f / 128.f) - mean * mean;
            msh[t] = mean;
            rsh[t] = rsqrtf(var + 1e-5f);
        }
        __syncthreads();
        // ---- coalesced write: 16-lane group per token row ----
        int p = t & 15;
        float4 gv0 = *(const float4*)&g[p * 8];
        float4 gv1 = *(const float4*)&g[p * 8 + 4];
        float4 bv0 = *(const float4*)&bta[p * 8];
        float4 bv1 = *(const float4*)&bta[p * 8 + 4];
#pragma unroll
        for (int it = 0; it < 8; ++it) {
            int cp = (t >> 4) + it * 16;                     // pixel column
            long n = (((long)b * 32 + (r >> 2)) * 32 + (cp >> 2)) * 16 +
                     ((r & 3) * 4 + (cp & 3));
            float mean = msh[cp], rstd = rsh[cp];
            bf16x8 pt, pn;
#pragma unroll
            for (int e = 0; e < 8; ++e) {
                float v = bf2f(tileB[p * 8 + e][cp]);
                float gg = (e < 4) ? ((const float*)&gv0)[e]
                                   : ((const float*)&gv1)[e - 4];
                float bb = (e < 4) ? ((const float*)&bv0)[e]
                                   : ((const float*)&bv1)[e - 4];
                pt[e] = (__bf16)v;
                pn[e] = (__bf16)((v - mean) * rstd * gg + bb);
            }
            *(bf16x8*)&xt[n * 128 + p * 8] = pt;
            *(bf16x8*)&xn[n * 128 + p * 8] = pn;
        }
    } else if (bid < 1280) {
        // ---- prep_A: A_T build, strip-mined to [128][66] (two 64-col passes)
        float (*tile)[66] = (float(*)[66])fbuf;              // 33792 B
        int bi = bid - 1024;  // 0..255
        int i = bi >> 4, k = bi & 15;
        int j = i ^ k;
        float s = (float)cd_sign(i, j);
        int lo = t & 127, hi = t >> 7;
        const float* src = sed_w + j * 16384;
        int a = t >> 1, cseg = (t & 1) * 32;
#pragma unroll
        for (int half = 0; half < 2; ++half) {
            int dbase = half * 64;
#pragma unroll
            for (int cc = 0; cc < 32; cc += 4) {
                float4 v = *(const float4*)&src[a * 128 + dbase + cseg + cc];
                tile[a][cseg + cc + 0] = v.x; tile[a][cseg + cc + 1] = v.y;
                tile[a][cseg + cc + 2] = v.z; tile[a][cseg + cc + 3] = v.w;
            }
            __syncthreads();
#pragma unroll
            for (int it = 0; it < 32; ++it) {
                int dl = it * 2 + hi;
                At[(long)(k * 128 + dbase + dl) * 2048 + i * 128 + lo] =
                    f2bf(s * tile[lo][dl]);
            }
            __syncthreads();
        }
    } else {
        // ---- prep_w: bf16 transposed weights --------------------------------
        int idx = (bid - 1280) * 256 + t;
        if (idx < 16384) {
            int d = idx >> 7, c = idx & 127;
            wpT[idx] = f2bf(wp[c * 128 + d]);              // wpT[d][c] = wp[c][d]
        } else if (idx < 16384 + 65536) {
            int e = idx - 16384;
            int o = e >> 7, c = e & 127;
            w1T[e] = f2bf(w1[c * 512 + o]);                // w1T[o][c] = w1[c][o]
        } else if (idx < 16384 + 131072) {
            int e = idx - 81920;
            int o = e >> 9, c = e & 511;
            w2T[e] = f2bf(w2[c * 128 + o]);                // w2T[o][c] = w2[c][o]
        }
    }
}

// ---------------- SED GEMM: 256x256 tile, BK=64, 8 waves, counted vmcnt -----
// (unchanged from round 4 -- verified, part of the 347->335 win)
__global__ __launch_bounds__(512, 2) void k_gemm_sed(const bf16* __restrict__ At,
                                                     const bf16* __restrict__ xn,
                                                     bf16* __restrict__ g_) {
    extern __shared__ __align__(16) char buf[];   // 131072 B
    const int t = threadIdx.x;
    const long bn = (long)blockIdx.x * 256;   // window base
    const long bm = (long)blockIdx.y * 256;   // kd base
    const int lane = t & 63;
    const int wid = t >> 6;          // 0..7
    const int wm2 = wid >> 2;        // A half (0/1): rows wm2*128..+128
    const int wn4 = wid & 3;         // B quarter: cols wn4*64..+64
    const int l15 = lane & 15, quad = lane >> 4;

    const int srow = t >> 3;                       // 0..63
    const int sslot = (t & 7) ^ (srow & 7);
    const bf16* gA0 = At + (bm + srow) * 2048L + sslot * 8;
    const bf16* gB0 = xn + (bn + srow) * 2048L + sslot * 8;

    char* const ldsA = buf;            // [d][h][row][64] : d*32768 + h*16384
    char* const ldsB = buf + 65536;

    const int ax0 = ((quad + 0) ^ (l15 & 7)) << 4;   // kk=0 swizzled byte slot
    const int ax1 = ((quad + 4) ^ (l15 & 7)) << 4;   // kk=1
    const int aRowBase = wm2 * 16384 + l15 * 128;
    const int bRowBase = (wn4 >> 1) * 16384 + ((wn4 & 1) * 64 + l15) * 128;

#define SED_STAGE(d, kt)                                                     \
    {                                                                        \
        const long k0_ = (long)(kt) * 64;                                    \
        char* la_ = ldsA + (d) * 32768;                                      \
        char* lb_ = ldsB + (d) * 32768;                                      \
        const bf16* ga_ = gA0 + k0_;                                         \
        const bf16* gb_ = gB0 + k0_;                                         \
        _Pragma("unroll")                                                    \
        for (int h_ = 0; h_ < 2; ++h_)                                       \
            _Pragma("unroll")                                                \
            for (int r_ = 0; r_ < 2; ++r_) {                                 \
                const long gro_ = (long)(h_ * 128 + r_ * 64) * 2048;         \
                const int lo_ = h_ * 16384 + r_ * 8192 + t * 16;             \
                async16(la_ + lo_, ga_ + gro_);                              \
                async16(lb_ + lo_, gb_ + gro_);                              \
            }                                                                \
    }

    SED_STAGE(0, 0);
    SED_STAGE(1, 1);

    f32x4 acc[8][4] = {};

    for (int tt = 0; tt < 32; ++tt) {
        const int d = tt & 1;
        if (tt < 31) asm volatile("s_waitcnt vmcnt(8)" ::: "memory");
        else         asm volatile("s_waitcnt vmcnt(0)" ::: "memory");
        __builtin_amdgcn_s_barrier();
        asm volatile("" ::: "memory");   // no LDS read hoists above this point

        char* const la = ldsA + d * 32768 + aRowBase;
        char* const lb = ldsB + d * 32768 + bRowBase;
#pragma unroll
        for (int p = 0; p < 4; ++p) {
            const int kk = p & 1, mh = p >> 1;
            const int xo = kk ? ax1 : ax0;
            bf16x8 af[4], bfr[4];
#pragma unroll
            for (int i = 0; i < 4; ++i)
                af[i] = *(const bf16x8*)(la + (mh * 4 + i) * 2048 + xo);
#pragma unroll
            for (int n = 0; n < 4; ++n)
                bfr[n] = *(const bf16x8*)(lb + n * 2048 + xo);
            __builtin_amdgcn_s_barrier();
            __builtin_amdgcn_s_setprio(1);
#pragma unroll
            for (int i = 0; i < 4; ++i)
#pragma unroll
                for (int n = 0; n < 4; ++n)
                    acc[mh * 4 + i][n] = __builtin_amdgcn_mfma_f32_16x16x32_bf16(
                        af[i], bfr[n], acc[mh * 4 + i][n], 0, 0, 0);
            __builtin_amdgcn_s_setprio(0);
            __builtin_amdgcn_s_barrier();
        }
        if (tt < 30) {
            asm volatile("" ::: "memory");  // stage must not hoist above barrier
            SED_STAGE(d, tt + 2);
        }
    }
#undef SED_STAGE

    // ---- epilogue: GELU + transpose to g_[win][kd] via swizzled LDS --------
    __syncthreads();
    bf16* sOut = (bf16*)buf;    // 256 win x 128 kd, pitch 256 B, slot-swizzled
#pragma unroll
    for (int p2 = 0; p2 < 2; ++p2) {
        if (wm2 == p2) {
#pragma unroll
            for (int m = 0; m < 8; ++m)
#pragma unroll
                for (int n = 0; n < 4; ++n) {
                    int win = wn4 * 64 + n * 16 + l15;
                    int kdl = m * 16 + quad * 4;         // 0..127
                    bf16x4 v;
#pragma unroll
                    for (int r = 0; r < 4; ++r)
                        v[r] = (__bf16)gelu_fast(acc[m][n][r]);
                    int slot = kdl >> 3;
                    int off = win * 256 + ((slot ^ (win & 7)) << 4) +
                              ((kdl * 2) & 15);
                    *(bf16x4*)((char*)sOut + off) = v;
                }
        }
        __syncthreads();
#pragma unroll
        for (int rr = 0; rr < 2; ++rr) {
            int win = (t >> 2) + rr * 128;
            int sub = t & 3;
#pragma unroll
            for (int j = 0; j < 4; ++j) {
                int c = j * 4 + sub;   // 16B chunk = 8 kd; sub innermost = 64B runs
                bf16x8 v = *(const bf16x8*)((char*)sOut + win * 256 +
                                            ((c ^ (win & 7)) << 4));
                *(bf16x8*)&g_[(bn + win) * 2048L + bm + p2 * 128 + c * 8] = v;
            }
        }
        __syncthreads();
    }
}

// ---------------- fused tail (round-0 structure, single hT) -----------------
// Latency-bound at ~108 us; occupancy 21-42% tested (r1-r8) with NO effect.
// Do not restructure further without new counter evidence.
__global__ __launch_bounds__(256, 2) void k_tail(
    const bf16* __restrict__ g_,   // (131072 x 128) token-major
    const bf16* __restrict__ wpT,  // (128 x 128)
    const float* __restrict__ bproj,
    const bf16* __restrict__ xt,   // residual (131072 x 128)
    const float* __restrict__ gamma2, const float* __restrict__ beta2,
    const bf16* __restrict__ w1T,  // (512 x 128)
    const float* __restrict__ b1,
    const bf16* __restrict__ w2T,  // (128 x 512)
    const float* __restrict__ b2,
    float* __restrict__ out)       // (8,128,128,128) fp32
{
    __shared__ __align__(16) char buf[53248];
    bf16* mpT = (bf16*)buf;                 // [token][channel] pitch 136 (34816 B)
    bf16* hT  = (bf16*)(buf + 34816);       // [token][hid64] pitch 72 (18432 B)
    float* stats = (float*)(buf + 34816);   // overlay on hT (dead until chunks)
    float* outF = (float*)buf;              // [slot64][token] pitch 132 (overlay mpT)

    int t = threadIdx.x;
    long tb = (long)blockIdx.x * 128;
    int lane = t & 63;
    int wm = ((t >> 7) & 1) * 64;    // channel half (proj / mlp2 / epilogues)
    int wm1 = ((t >> 7) & 1) * 32;   // hidden half within a 64-chunk (mlp1)
    int wn = ((t >> 6) & 1) * 64;    // token half
    int l15 = lane & 15, quad = lane >> 4;
    int half = wm >> 6;

    int tok[4];
#pragma unroll
    for (int tn = 0; tn < 4; ++tn) tok[tn] = wn + tn * 16 + l15;

    // ---- proj (transposed): acc1[d][tok] = wpT @ g_^T ----
    f32x4 acc1[4][4] = {};
#pragma unroll
    for (int k0 = 0; k0 < 128; k0 += 32) {
        bf16x8 af[4], bfr[4];
#pragma unroll
        for (int tm = 0; tm < 4; ++tm)
            af[tm] = *(const bf16x8*)&wpT[(wm + tm * 16 + l15) * 128 + k0 + quad * 8];
#pragma unroll
        for (int tn = 0; tn < 4; ++tn)
            bfr[tn] = *(const bf16x8*)&g_[(tb + tok[tn]) * 128 + k0 + quad * 8];
#pragma unroll
        for (int tm = 0; tm < 4; ++tm)
#pragma unroll
            for (int tn = 0; tn < 4; ++tn)
                acc1[tm][tn] = __builtin_amdgcn_mfma_f32_16x16x32_bf16(
                    af[tm], bfr[tn], acc1[tm][tn], 0, 0, 0);
    }

    // ---- + bproj[channel] + xt[token][channel] ----
#pragma unroll
    for (int tm = 0; tm < 4; ++tm) {
        int c0 = wm + tm * 16 + quad * 4;
        float4 bp = *(const float4*)&bproj[c0];
#pragma unroll
        for (int tn = 0; tn < 4; ++tn) {
            bf16x4 xv = *(const bf16x4*)&xt[(tb + tok[tn]) * 128 + c0];
#pragma unroll
            for (int reg = 0; reg < 4; ++reg)
                acc1[tm][tn][reg] += ((const float*)&bp)[reg] + (float)xv[reg];
        }
    }

    // ---- LN2 stats ----
#pragma unroll
    for (int tn = 0; tn < 4; ++tn) {
        float s = 0.f, ss = 0.f;
#pragma unroll
        for (int tm = 0; tm < 4; ++tm)
#pragma unroll
            for (int reg = 0; reg < 4; ++reg) {
                float v = acc1[tm][tn][reg];
                s += v; ss += v * v;
            }
        s += __shfl_xor(s, 16); ss += __shfl_xor(ss, 16);
        s += __shfl_xor(s, 32); ss += __shfl_xor(ss, 32);
        if (quad == 0) {
            stats[tok[tn] * 2 + half] = s;
            stats[256 + tok[tn] * 2 + half] = ss;
        }
    }
    __syncthreads();

    // ---- LN apply -> mpT [token][channel] ----
    float mean[4], rstd[4];
#pragma unroll
    for (int tn = 0; tn < 4; ++tn) {
        float S = stats[tok[tn] * 2] + stats[tok[tn] * 2 + 1];
        float SS = stats[256 + tok[tn] * 2] + stats[256 + tok[tn] * 2 + 1];
        mean[tn] = S * (1.f / 128.f);
        float var = SS * (1.f / 128.f) - mean[tn] * mean[tn];
        rstd[tn] = rsqrtf(var + 1e-5f);
    }
#pragma unroll
    for (int tm = 0; tm < 4; ++tm) {
        int c0 = wm + tm * 16 + quad * 4;
        float4 gv = *(const float4*)&gamma2[c0];
        float4 bv = *(const float4*)&beta2[c0];
#pragma unroll
        for (int tn = 0; tn < 4; ++tn) {
            bf16x4 p;
#pragma unroll
            for (int reg = 0; reg < 4; ++reg)
                p[reg] = (__bf16)((acc1[tm][tn][reg] - mean[tn]) * rstd[tn] *
                                      ((const float*)&gv)[reg] +
                                  ((const float*)&bv)[reg]);
            *(bf16x4*)&mpT[tok[tn] * 136 + c0] = p;
        }
    }
    __syncthreads();

    // ---- MLP: 8 hidden chunks of 64; single hT, 2 barriers/chunk ----
    f32x4 acc2[4][4] = {};
    for (int oh = 0; oh < 8; ++oh) {
        f32x4 acch[2][4] = {};
#pragma unroll
        for (int k0 = 0; k0 < 128; k0 += 32) {
            bf16x8 af[2], bfr[4];
#pragma unroll
            for (int tm = 0; tm < 2; ++tm)
                af[tm] = *(const bf16x8*)&w1T[(oh * 64 + wm1 + tm * 16 + l15) * 128 +
                                              k0 + quad * 8];
#pragma unroll
            for (int tn = 0; tn < 4; ++tn)
                bfr[tn] = *(const bf16x8*)&mpT[tok[tn] * 136 + k0 + quad * 8];
#pragma unroll
            for (int tm = 0; tm < 2; ++tm)
#pragma unroll
                for (int tn = 0; tn < 4; ++tn)
                    acch[tm][tn] = __builtin_amdgcn_mfma_f32_16x16x32_bf16(
                        af[tm], bfr[tn], acch[tm][tn], 0, 0, 0);
        }
        // prev chunk's MLP2 must finish reading hT before overwrite
        __syncthreads();
        // GELU + b1 -> hT [token][hid64] pitch 72
#pragma unroll
        for (int tm = 0; tm < 2; ++tm) {
            int hc0 = wm1 + tm * 16 + quad * 4;   // local hidden in [0,64)
            float4 bh = *(const float4*)&b1[oh * 64 + hc0];
#pragma unroll
            for (int tn = 0; tn < 4; ++tn) {
                bf16x4 p;
#pragma unroll
                for (int reg = 0; reg < 4; ++reg)
                    p[reg] = (__bf16)gelu_fast(acch[tm][tn][reg] +
                                               ((const float*)&bh)[reg]);
                *(bf16x4*)&hT[tok[tn] * 72 + hc0] = p;
            }
        }
        __syncthreads();
        // MLP2 partial: acc2 += w2T-chunk @ hT^T  (K = 64)
#pragma unroll
        for (int k0 = 0; k0 < 64; k0 += 32) {
            bf16x8 af[4], bfr[4];
#pragma unroll
            for (int tm = 0; tm < 4; ++tm)
                af[tm] = *(const bf16x8*)&w2T[(wm + tm * 16 + l15) * 512 +
                                              oh * 64 + k0 + quad * 8];
#pragma unroll
            for (int tn = 0; tn < 4; ++tn)
                bfr[tn] = *(const bf16x8*)&hT[tok[tn] * 72 + k0 + quad * 8];
#pragma unroll
            for (int tm = 0; tm < 4; ++tm)
#pragma unroll
                for (int tn = 0; tn < 4; ++tn)
                    acc2[tm][tn] = __builtin_amdgcn_mfma_f32_16x16x32_bf16(
                        af[tm], bfr[tn], acc2[tm][tn], 0, 0, 0);
        }
    }
    __syncthreads();

    // ---- final: out = y2 + mlp2 + b2 in two 64-channel LDS passes ----
    long win0 = tb >> 4;
    int b = (int)(win0 >> 10);
    int hq = (int)(win0 >> 5) & 31;
    int wq0 = (int)win0 & 31;
#pragma unroll
    for (int p = 0; p < 2; ++p) {
#pragma unroll
        for (int tmi = 0; tmi < 2; ++tmi) {
            int tm = p * 2 + tmi;
            int c0 = wm + tm * 16 + quad * 4;
            int slot0 = (wm >> 1) + tmi * 16 + quad * 4;
            float4 bv = *(const float4*)&b2[c0];
#pragma unroll
            for (int tn = 0; tn < 4; ++tn)
#pragma unroll
                for (int reg = 0; reg < 4; ++reg)
                    outF[(slot0 + reg) * 132 + tok[tn]] =
                        acc1[tm][tn][reg] + acc2[tm][tn][reg] +
                        ((const float*)&bv)[reg];
        }
        __syncthreads();
#pragma unroll
        for (int it = 0; it < 8; ++it) {
            int id = it * 256 + t;
            int slot = id >> 5, rem = id & 31;
            int rr = rem >> 3, wqo = rem & 7;
            int c = slot + ((slot >= 32) ? 32 : 0) + p * 32;
            f32x4 v = *(const f32x4*)&outF[slot * 132 + wqo * 16 + rr * 4];
            long addr = (((long)b * 128 + c) * 128 + hq * 4 + rr) * 128 +
                        (wq0 + wqo) * 4;
            *(f32x4*)&out[addr] = v;
        }
        __syncthreads();
    }
}

extern "C" void kernel_launch(void* const* d_in, const int* in_sizes, int n_in,
                              void* d_out, int out_size, void* d_ws, size_t ws_size,
                              hipStream_t stream) {
    const float* x      = (const float*)d_in[0];
    const float* gamma1 = (const float*)d_in[1];
    const float* beta1  = (const float*)d_in[2];
    const float* sed_w  = (const float*)d_in[3];
    const float* w_proj = (const float*)d_in[4];
    const float* b_proj = (const float*)d_in[5];
    const float* gamma2 = (const float*)d_in[6];
    const float* beta2  = (const float*)d_in[7];
    const float* w1     = (const float*)d_in[8];
    const float* b1     = (const float*)d_in[9];
    const float* w2     = (const float*)d_in[10];
    const float* b2     = (const float*)d_in[11];

    char* ws = (char*)d_ws;
    bf16* At  = (bf16*)(ws + 0);           //  8,388,608
    bf16* wpT = (bf16*)(ws + 8388608);     //     32,768
    bf16* w1T = (bf16*)(ws + 8421376);     //    131,072
    bf16* w2T = (bf16*)(ws + 8552448);     //    131,072
    bf16* xt  = (bf16*)(ws + 8683520);     // 33,554,432
    bf16* xn  = (bf16*)(ws + 42237952);    // 33,554,432
    bf16* g_  = (bf16*)(ws + 75792384);    // 33,554,432

    // fused front: ln1 (blocks 0-1023) + prep_A (1024-1279) + prep_w (1280-1855)
    hipLaunchKernelGGL(k_front, dim3(1856), dim3(256), 0, stream,
                       x, gamma1, beta1, sed_w, w_proj, w1, w2,
                       xt, xn, At, wpT, w1T, w2T);
    // SED: 256x256 tiles; grid x = 8192/256 win-blocks, y = 2048/256 kd-blocks
    hipLaunchKernelGGL(k_gemm_sed, dim3(32, 8), dim3(512), 131072, stream,
                       At, xn, g_);
    // fused tail: proj + res + LN2 + MLP + res + un-permute + fp32 out
    hipLaunchKernelGGL(k_tail, dim3(1024), dim3(256), 0, stream,
                       g_, wpT, b_proj, xt, gamma2, beta2,
                       w1T, b1, w2T, b2, (float*)d_out);
}

// Round 13
// 307.162 us; speedup vs baseline: 1.0301x; 1.0301x over previous
//
#include <hip/hip_runtime.h>
#include <hip/hip_bf16.h>

#define DEVI __device__ __forceinline__

typedef __attribute__((ext_vector_type(8))) __bf16 bf16x8;
typedef __attribute__((ext_vector_type(4))) __bf16 bf16x4;
typedef __attribute__((ext_vector_type(4))) float f32x4;

using bf16 = __hip_bfloat16;

DEVI float bf2f(bf16 v) { return __bfloat162float(v); }
DEVI bf16 f2bf(float v) { return __float2bfloat16(v); }

// tanh-form GELU; max |diff vs exact| ~3e-3, under bf16 epilogue noise.
DEVI float gelu_fast(float v) {
    float t = v * (2.30220777f + 0.10294322f * v * v);
    float e = __builtin_amdgcn_exp2f(t);
    return v - v * __builtin_amdgcn_rcpf(e + 1.0f);
}

DEVI void async16(void* lds, const void* g) {
    __builtin_amdgcn_global_load_lds(
        (const __attribute__((address_space(1))) void*)g,
        (__attribute__((address_space(3))) void*)lds, 16, 0, 0);
}

// sign of e_i * e_j in 16-dim Cayley-Dickson algebra (index is i^j)
DEVI int cd_sign(int i, int j) {
    int s = 1, n = 16;
    while (n > 1) {
        int h = n >> 1;
        int ih = (i >= h), jh = (j >= h);
        if (!ih && !jh) {
        } else if (!ih && jh) {
            int ni = j - h, nj = i;
            i = ni; j = nj;
        } else if (ih && !jh) {
            if (j != 0) s = -s;
            i = i - h;
        } else {
            int ni = j - h, nj = i - h;
            if (ni == 0) s = -s;
            i = ni; j = nj;
        }
        n = h;
    }
    return s;
}

// ---------------- fused front: ln1 (1024 blk) + prep_A (256) + prep_w (576) --
// Round-10 version (best measured: 309.4 us total).  r11's LDS-shrink variant
// (39936 B, bf16 tile, strip-mined prep_A) regressed +5-7 us -- reverted.
// ln1: float4 loads, coalesced 1-KB-run stores via 16-lane-group-per-token.
__global__ __launch_bounds__(256) void k_front(
    const float* __restrict__ x, const float* __restrict__ g,
    const float* __restrict__ bta, const float* __restrict__ sed_w,
    const float* __restrict__ wp, const float* __restrict__ w1,
    const float* __restrict__ w2,
    bf16* __restrict__ xt, bf16* __restrict__ xn, bf16* __restrict__ At,
    bf16* __restrict__ wpT, bf16* __restrict__ w1T, bf16* __restrict__ w2T) {
    __shared__ __align__(16) char fbuf[69120];
    int bid = blockIdx.x;
    int t = threadIdx.x;

    if (bid < 1024) {
        // ---- LN1 + transpose to window-permuted token order ----------------
        float (*tile)[129] = (float(*)[129])fbuf;            // 66048 B
        float* ps  = (float*)(fbuf + 66048);                 // [2][128]
        float* pss = (float*)(fbuf + 67072);                 // [2][128]
        float* msh = (float*)(fbuf + 68096);                 // mean[128]
        float* rsh = (float*)(fbuf + 68608);                 // rstd[128]
        int b = bid >> 7, r = bid & 127;
        int c = t & 127, half = t >> 7;
        const float* xb = x + ((long)b * 128 * 128 + r) * 128;
        int grp = t >> 5;            // 0..7
        int c4 = (t & 31) * 4;       // float4 column base
#pragma unroll
        for (int it = 0; it < 16; ++it) {
            int ch = it * 8 + grp;
            float4 v = *(const float4*)&xb[(long)ch * 16384 + c4];
            tile[ch][c4 + 0] = v.x; tile[ch][c4 + 1] = v.y;
            tile[ch][c4 + 2] = v.z; tile[ch][c4 + 3] = v.w;
        }
        __syncthreads();
        float s = 0.f, ss = 0.f;
        for (int ch = half * 64; ch < half * 64 + 64; ++ch) {
            float v = tile[ch][c];
            s += v; ss += v * v;
        }
        ps[half * 128 + c] = s; pss[half * 128 + c] = ss;
        __syncthreads();
        {
            float S = ps[c] + ps[128 + c], SS = pss[c] + pss[128 + c];
            float mean = S * (1.f / 128.f);
            float var = SS * (1.f / 128.f) - mean * mean;
            float rstd = rsqrtf(var + 1e-5f);
            if (half == 0) { msh[c] = mean; rsh[c] = rstd; }
        }
        __syncthreads();
        // ---- coalesced write: 16-lane group per token row ----
        int p = t & 15;
        float4 gv0 = *(const float4*)&g[p * 8];
        float4 gv1 = *(const float4*)&g[p * 8 + 4];
        float4 bv0 = *(const float4*)&bta[p * 8];
        float4 bv1 = *(const float4*)&bta[p * 8 + 4];
#pragma unroll
        for (int it = 0; it < 8; ++it) {
            int cp = (t >> 4) + it * 16;                     // pixel column
            long n = (((long)b * 32 + (r >> 2)) * 32 + (cp >> 2)) * 16 +
                     ((r & 3) * 4 + (cp & 3));
            float mean = msh[cp], rstd = rsh[cp];
            bf16x8 pt, pn;
#pragma unroll
            for (int e = 0; e < 8; ++e) {
                float v = tile[p * 8 + e][cp];
                float gg = (e < 4) ? ((const float*)&gv0)[e]
                                   : ((const float*)&gv1)[e - 4];
                float bb = (e < 4) ? ((const float*)&bv0)[e]
                                   : ((const float*)&bv1)[e - 4];
                pt[e] = (__bf16)v;
                pn[e] = (__bf16)((v - mean) * rstd * gg + bb);
            }
            *(bf16x8*)&xt[n * 128 + p * 8] = pt;
            *(bf16x8*)&xn[n * 128 + p * 8] = pn;
        }
    } else if (bid < 1280) {
        // ---- prep_A: build A_T (2048x2048 bf16), row (k,d), col (i,c) ------
        float (*tile)[129] = (float(*)[129])fbuf;            // 66048 B
        int bi = bid - 1024;  // 0..255
        int i = bi >> 4, k = bi & 15;
        int j = i ^ k;
        float s = (float)cd_sign(i, j);
        int lo = t & 127, hi = t >> 7;
        const float* src = sed_w + j * 16384;
        for (int it = 0; it < 64; ++it) {
            int c = it * 2 + hi;
            tile[c][lo] = src[c * 128 + lo];
        }
        __syncthreads();
        for (int it = 0; it < 64; ++it) {
            int d = it * 2 + hi;
            At[(long)(k * 128 + d) * 2048 + i * 128 + lo] = f2bf(s * tile[lo][d]);
        }
    } else {
        // ---- prep_w: bf16 transposed weights --------------------------------
        int idx = (bid - 1280) * 256 + t;
        if (idx < 16384) {
            int d = idx >> 7, c = idx & 127;
            wpT[idx] = f2bf(wp[c * 128 + d]);              // wpT[d][c] = wp[c][d]
        } else if (idx < 16384 + 65536) {
            int e = idx - 16384;
            int o = e >> 7, c = e & 127;
            w1T[e] = f2bf(w1[c * 512 + o]);                // w1T[o][c] = w1[c][o]
        } else if (idx < 16384 + 131072) {
            int e = idx - 81920;
            int o = e >> 9, c = e & 511;
            w2T[e] = f2bf(w2[c * 128 + o]);                // w2T[o][c] = w2[c][o]
        }
    }
}

// ---------------- SED GEMM: 256x256 tile, BK=64, 8 waves, counted vmcnt -----
// v2: __launch_bounds__(512, 1).  The previous (512,2) bound imposed a
// 128-VGPR/wave cap, but acc[8][4] f32x4 is 128 VGPRs ALONE (+32 frags
// +~20 addr) => the K-loop has been spilling ~80 regs to scratch since r4
// (invisible: sed never surfaced in top-5 counters).  LDS 128 KiB already
// limits to 1 block/CU, so (512,1) costs nothing and lifts the cap to 256.
__global__ __launch_bounds__(512, 1) void k_gemm_sed(const bf16* __restrict__ At,
                                                     const bf16* __restrict__ xn,
                                                     bf16* __restrict__ g_) {
    extern __shared__ __align__(16) char buf[];   // 131072 B
    const int t = threadIdx.x;
    const long bn = (long)blockIdx.x * 256;   // window base
    const long bm = (long)blockIdx.y * 256;   // kd base
    const int lane = t & 63;
    const int wid = t >> 6;          // 0..7
    const int wm2 = wid >> 2;        // A half (0/1): rows wm2*128..+128
    const int wn4 = wid & 3;         // B quarter: cols wn4*64..+64
    const int l15 = lane & 15, quad = lane >> 4;

    const int srow = t >> 3;                       // 0..63
    const int sslot = (t & 7) ^ (srow & 7);
    const bf16* gA0 = At + (bm + srow) * 2048L + sslot * 8;
    const bf16* gB0 = xn + (bn + srow) * 2048L + sslot * 8;

    char* const ldsA = buf;            // [d][h][row][64] : d*32768 + h*16384
    char* const ldsB = buf + 65536;

    const int ax0 = ((quad + 0) ^ (l15 & 7)) << 4;   // kk=0 swizzled byte slot
    const int ax1 = ((quad + 4) ^ (l15 & 7)) << 4;   // kk=1
    const int aRowBase = wm2 * 16384 + l15 * 128;
    const int bRowBase = (wn4 >> 1) * 16384 + ((wn4 & 1) * 64 + l15) * 128;

#define SED_STAGE(d, kt)                                                     \
    {                                                                        \
        const long k0_ = (long)(kt) * 64;                                    \
        char* la_ = ldsA + (d) * 32768;                                      \
        char* lb_ = ldsB + (d) * 32768;                                      \
        const bf16* ga_ = gA0 + k0_;                                         \
        const bf16* gb_ = gB0 + k0_;                                         \
        _Pragma("unroll")                                                    \
        for (int h_ = 0; h_ < 2; ++h_)                                       \
            _Pragma("unroll")                                                \
            for (int r_ = 0; r_ < 2; ++r_) {                                 \
                const long gro_ = (long)(h_ * 128 + r_ * 64) * 2048;         \
                const int lo_ = h_ * 16384 + r_ * 8192 + t * 16;             \
                async16(la_ + lo_, ga_ + gro_);                              \
                async16(lb_ + lo_, gb_ + gro_);                              \
            }                                                                \
    }

    SED_STAGE(0, 0);
    SED_STAGE(1, 1);

    f32x4 acc[8][4] = {};

    for (int tt = 0; tt < 32; ++tt) {
        const int d = tt & 1;
        if (tt < 31) asm volatile("s_waitcnt vmcnt(8)" ::: "memory");
        else         asm volatile("s_waitcnt vmcnt(0)" ::: "memory");
        __builtin_amdgcn_s_barrier();
        asm volatile("" ::: "memory");   // no LDS read hoists above this point

        char* const la = ldsA + d * 32768 + aRowBase;
        char* const lb = ldsB + d * 32768 + bRowBase;
#pragma unroll
        for (int p = 0; p < 4; ++p) {
            const int kk = p & 1, mh = p >> 1;
            const int xo = kk ? ax1 : ax0;
            bf16x8 af[4], bfr[4];
#pragma unroll
            for (int i = 0; i < 4; ++i)
                af[i] = *(const bf16x8*)(la + (mh * 4 + i) * 2048 + xo);
#pragma unroll
            for (int n = 0; n < 4; ++n)
                bfr[n] = *(const bf16x8*)(lb + n * 2048 + xo);
            __builtin_amdgcn_s_barrier();
            __builtin_amdgcn_s_setprio(1);
#pragma unroll
            for (int i = 0; i < 4; ++i)
#pragma unroll
                for (int n = 0; n < 4; ++n)
                    acc[mh * 4 + i][n] = __builtin_amdgcn_mfma_f32_16x16x32_bf16(
                        af[i], bfr[n], acc[mh * 4 + i][n], 0, 0, 0);
            __builtin_amdgcn_s_setprio(0);
            __builtin_amdgcn_s_barrier();
        }
        if (tt < 30) {
            asm volatile("" ::: "memory");  // stage must not hoist above barrier
            SED_STAGE(d, tt + 2);
        }
    }
#undef SED_STAGE

    // ---- epilogue: GELU + transpose to g_[win][kd] via swizzled LDS --------
    __syncthreads();
    bf16* sOut = (bf16*)buf;    // 256 win x 128 kd, pitch 256 B, slot-swizzled
#pragma unroll
    for (int p2 = 0; p2 < 2; ++p2) {
        if (wm2 == p2) {
#pragma unroll
            for (int m = 0; m < 8; ++m)
#pragma unroll
                for (int n = 0; n < 4; ++n) {
                    int win = wn4 * 64 + n * 16 + l15;
                    int kdl = m * 16 + quad * 4;         // 0..127
                    bf16x4 v;
#pragma unroll
                    for (int r = 0; r < 4; ++r)
                        v[r] = (__bf16)gelu_fast(acc[m][n][r]);
                    int slot = kdl >> 3;
                    int off = win * 256 + ((slot ^ (win & 7)) << 4) +
                              ((kdl * 2) & 15);
                    *(bf16x4*)((char*)sOut + off) = v;
                }
        }
        __syncthreads();
#pragma unroll
        for (int rr = 0; rr < 2; ++rr) {
            int win = (t >> 2) + rr * 128;
            int sub = t & 3;
#pragma unroll
            for (int j = 0; j < 4; ++j) {
                int c = j * 4 + sub;   // 16B chunk = 8 kd; sub innermost = 64B runs
                bf16x8 v = *(const bf16x8*)((char*)sOut + win * 256 +
                                            ((c ^ (win & 7)) << 4));
                *(bf16x8*)&g_[(bn + win) * 2048L + bm + p2 * 128 + c * 8] = v;
            }
        }
        __syncthreads();
    }
}

// ---------------- fused tail (round-0 structure, single hT) -----------------
// Latency-bound at ~108 us; occupancy 21-42% tested (r1-r8) with NO effect.
// Do not restructure further without new counter evidence.
__global__ __launch_bounds__(256, 2) void k_tail(
    const bf16* __restrict__ g_,   // (131072 x 128) token-major
    const bf16* __restrict__ wpT,  // (128 x 128)
    const float* __restrict__ bproj,
    const bf16* __restrict__ xt,   // residual (131072 x 128)
    const float* __restrict__ gamma2, const float* __restrict__ beta2,
    const bf16* __restrict__ w1T,  // (512 x 128)
    const float* __restrict__ b1,
    const bf16* __restrict__ w2T,  // (128 x 512)
    const float* __restrict__ b2,
    float* __restrict__ out)       // (8,128,128,128) fp32
{
    __shared__ __align__(16) char buf[53248];
    bf16* mpT = (bf16*)buf;                 // [token][channel] pitch 136 (34816 B)
    bf16* hT  = (bf16*)(buf + 34816);       // [token][hid64] pitch 72 (18432 B)
    float* stats = (float*)(buf + 34816);   // overlay on hT (dead until chunks)
    float* outF = (float*)buf;              // [slot64][token] pitch 132 (overlay mpT)

    int t = threadIdx.x;
    long tb = (long)blockIdx.x * 128;
    int lane = t & 63;
    int wm = ((t >> 7) & 1) * 64;    // channel half (proj / mlp2 / epilogues)
    int wm1 = ((t >> 7) & 1) * 32;   // hidden half within a 64-chunk (mlp1)
    int wn = ((t >> 6) & 1) * 64;    // token half
    int l15 = lane & 15, quad = lane >> 4;
    int half = wm >> 6;

    int tok[4];
#pragma unroll
    for (int tn = 0; tn < 4; ++tn) tok[tn] = wn + tn * 16 + l15;

    // ---- proj (transposed): acc1[d][tok] = wpT @ g_^T ----
    f32x4 acc1[4][4] = {};
#pragma unroll
    for (int k0 = 0; k0 < 128; k0 += 32) {
        bf16x8 af[4], bfr[4];
#pragma unroll
        for (int tm = 0; tm < 4; ++tm)
            af[tm] = *(const bf16x8*)&wpT[(wm + tm * 16 + l15) * 128 + k0 + quad * 8];
#pragma unroll
        for (int tn = 0; tn < 4; ++tn)
            bfr[tn] = *(const bf16x8*)&g_[(tb + tok[tn]) * 128 + k0 + quad * 8];
#pragma unroll
        for (int tm = 0; tm < 4; ++tm)
#pragma unroll
            for (int tn = 0; tn < 4; ++tn)
                acc1[tm][tn] = __builtin_amdgcn_mfma_f32_16x16x32_bf16(
                    af[tm], bfr[tn], acc1[tm][tn], 0, 0, 0);
    }

    // ---- + bproj[channel] + xt[token][channel] ----
#pragma unroll
    for (int tm = 0; tm < 4; ++tm) {
        int c0 = wm + tm * 16 + quad * 4;
        float4 bp = *(const float4*)&bproj[c0];
#pragma unroll
        for (int tn = 0; tn < 4; ++tn) {
            bf16x4 xv = *(const bf16x4*)&xt[(tb + tok[tn]) * 128 + c0];
#pragma unroll
            for (int reg = 0; reg < 4; ++reg)
                acc1[tm][tn][reg] += ((const float*)&bp)[reg] + (float)xv[reg];
        }
    }

    // ---- LN2 stats ----
#pragma unroll
    for (int tn = 0; tn < 4; ++tn) {
        float s = 0.f, ss = 0.f;
#pragma unroll
        for (int tm = 0; tm < 4; ++tm)
#pragma unroll
            for (int reg = 0; reg < 4; ++reg) {
                float v = acc1[tm][tn][reg];
                s += v; ss += v * v;
            }
        s += __shfl_xor(s, 16); ss += __shfl_xor(ss, 16);
        s += __shfl_xor(s, 32); ss += __shfl_xor(ss, 32);
        if (quad == 0) {
            stats[tok[tn] * 2 + half] = s;
            stats[256 + tok[tn] * 2 + half] = ss;
        }
    }
    __syncthreads();

    // ---- LN apply -> mpT [token][channel] ----
    float mean[4], rstd[4];
#pragma unroll
    for (int tn = 0; tn < 4; ++tn) {
        float S = stats[tok[tn] * 2] + stats[tok[tn] * 2 + 1];
        float SS = stats[256 + tok[tn] * 2] + stats[256 + tok[tn] * 2 + 1];
        mean[tn] = S * (1.f / 128.f);
        float var = SS * (1.f / 128.f) - mean[tn] * mean[tn];
        rstd[tn] = rsqrtf(var + 1e-5f);
    }
#pragma unroll
    for (int tm = 0; tm < 4; ++tm) {
        int c0 = wm + tm * 16 + quad * 4;
        float4 gv = *(const float4*)&gamma2[c0];
        float4 bv = *(const float4*)&beta2[c0];
#pragma unroll
        for (int tn = 0; tn < 4; ++tn) {
            bf16x4 p;
#pragma unroll
            for (int reg = 0; reg < 4; ++reg)
                p[reg] = (__bf16)((acc1[tm][tn][reg] - mean[tn]) * rstd[tn] *
                                      ((const float*)&gv)[reg] +
                                  ((const float*)&bv)[reg]);
            *(bf16x4*)&mpT[tok[tn] * 136 + c0] = p;
        }
    }
    __syncthreads();

    // ---- MLP: 8 hidden chunks of 64; single hT, 2 barriers/chunk ----
    f32x4 acc2[4][4] = {};
    for (int oh = 0; oh < 8; ++oh) {
        f32x4 acch[2][4] = {};
#pragma unroll
        for (int k0 = 0; k0 < 128; k0 += 32) {
            bf16x8 af[2], bfr[4];
#pragma unroll
            for (int tm = 0; tm < 2; ++tm)
                af[tm] = *(const bf16x8*)&w1T[(oh * 64 + wm1 + tm * 16 + l15) * 128 +
                                              k0 + quad * 8];
#pragma unroll
            for (int tn = 0; tn < 4; ++tn)
                bfr[tn] = *(const bf16x8*)&mpT[tok[tn] * 136 + k0 + quad * 8];
#pragma unroll
            for (int tm = 0; tm < 2; ++tm)
#pragma unroll
                for (int tn = 0; tn < 4; ++tn)
                    acch[tm][tn] = __builtin_amdgcn_mfma_f32_16x16x32_bf16(
                        af[tm], bfr[tn], acch[tm][tn], 0, 0, 0);
        }
        // prev chunk's MLP2 must finish reading hT before overwrite
        __syncthreads();
        // GELU + b1 -> hT [token][hid64] pitch 72
#pragma unroll
        for (int tm = 0; tm < 2; ++tm) {
            int hc0 = wm1 + tm * 16 + quad * 4;   // local hidden in [0,64)
            float4 bh = *(const float4*)&b1[oh * 64 + hc0];
#pragma unroll
            for (int tn = 0; tn < 4; ++tn) {
                bf16x4 p;
#pragma unroll
                for (int reg = 0; reg < 4; ++reg)
                    p[reg] = (__bf16)gelu_fast(acch[tm][tn][reg] +
                                               ((const float*)&bh)[reg]);
                *(bf16x4*)&hT[tok[tn] * 72 + hc0] = p;
            }
        }
        __syncthreads();
        // MLP2 partial: acc2 += w2T-chunk @ hT^T  (K = 64)
#pragma unroll
        for (int k0 = 0; k0 < 64; k0 += 32) {
            bf16x8 af[4], bfr[4];
#pragma unroll
            for (int tm = 0; tm < 4; ++tm)
                af[tm] = *(const bf16x8*)&w2T[(wm + tm * 16 + l15) * 512 +
                                              oh * 64 + k0 + quad * 8];
#pragma unroll
            for (int tn = 0; tn < 4; ++tn)
                bfr[tn] = *(const bf16x8*)&hT[tok[tn] * 72 + k0 + quad * 8];
#pragma unroll
            for (int tm = 0; tm < 4; ++tm)
#pragma unroll
                for (int tn = 0; tn < 4; ++tn)
                    acc2[tm][tn] = __builtin_amdgcn_mfma_f32_16x16x32_bf16(
                        af[tm], bfr[tn], acc2[tm][tn], 0, 0, 0);
        }
    }
    __syncthreads();

    // ---- final: out = y2 + mlp2 + b2 in two 64-channel LDS passes ----
    long win0 = tb >> 4;
    int b = (int)(win0 >> 10);
    int hq = (int)(win0 >> 5) & 31;
    int wq0 = (int)win0 & 31;
#pragma unroll
    for (int p = 0; p < 2; ++p) {
#pragma unroll
        for (int tmi = 0; tmi < 2; ++tmi) {
            int tm = p * 2 + tmi;
            int c0 = wm + tm * 16 + quad * 4;
            int slot0 = (wm >> 1) + tmi * 16 + quad * 4;
            float4 bv = *(const float4*)&b2[c0];
#pragma unroll
            for (int tn = 0; tn < 4; ++tn)
#pragma unroll
                for (int reg = 0; reg < 4; ++reg)
                    outF[(slot0 + reg) * 132 + tok[tn]] =
                        acc1[tm][tn][reg] + acc2[tm][tn][reg] +
                        ((const float*)&bv)[reg];
        }
        __syncthreads();
#pragma unroll
        for (int it = 0; it < 8; ++it) {
            int id = it * 256 + t;
            int slot = id >> 5, rem = id & 31;
            int rr = rem >> 3, wqo = rem & 7;
            int c = slot + ((slot >= 32) ? 32 : 0) + p * 32;
            f32x4 v = *(const f32x4*)&outF[slot * 132 + wqo * 16 + rr * 4];
            long addr = (((long)b * 128 + c) * 128 + hq * 4 + rr) * 128 +
                        (wq0 + wqo) * 4;
            *(f32x4*)&out[addr] = v;
        }
        __syncthreads();
    }
}

extern "C" void kernel_launch(void* const* d_in, const int* in_sizes, int n_in,
                              void* d_out, int out_size, void* d_ws, size_t ws_size,
                              hipStream_t stream) {
    const float* x      = (const float*)d_in[0];
    const float* gamma1 = (const float*)d_in[1];
    const float* beta1  = (const float*)d_in[2];
    const float* sed_w  = (const float*)d_in[3];
    const float* w_proj = (const float*)d_in[4];
    const float* b_proj = (const float*)d_in[5];
    const float* gamma2 = (const float*)d_in[6];
    const float* beta2  = (const float*)d_in[7];
    const float* w1     = (const float*)d_in[8];
    const float* b1     = (const float*)d_in[9];
    const float* w2     = (const float*)d_in[10];
    const float* b2     = (const float*)d_in[11];

    char* ws = (char*)d_ws;
    bf16* At  = (bf16*)(ws + 0);           //  8,388,608
    bf16* wpT = (bf16*)(ws + 8388608);     //     32,768
    bf16* w1T = (bf16*)(ws + 8421376);     //    131,072
    bf16* w2T = (bf16*)(ws + 8552448);     //    131,072
    bf16* xt  = (bf16*)(ws + 8683520);     // 33,554,432
    bf16* xn  = (bf16*)(ws + 42237952);    // 33,554,432
    bf16* g_  = (bf16*)(ws + 75792384);    // 33,554,432

    // fused front: ln1 (blocks 0-1023) + prep_A (1024-1279) + prep_w (1280-1855)
    hipLaunchKernelGGL(k_front, dim3(1856), dim3(256), 0, stream,
                       x, gamma1, beta1, sed_w, w_proj, w1, w2,
                       xt, xn, At, wpT, w1T, w2T);
    // SED: 256x256 tiles; grid x = 8192/256 win-blocks, y = 2048/256 kd-blocks
    hipLaunchKernelGGL(k_gemm_sed, dim3(32, 8), dim3(512), 131072, stream,
                       At, xn, g_);
    // fused tail: proj + res + LN2 + MLP + res + un-permute + fp32 out
    hipLaunchKernelGGL(k_tail, dim3(1024), dim3(256), 0, stream,
                       g_, wpT, b_proj, xt, gamma2, beta2,
                       w1T, b1, w2T, b2, (float*)d_out);
}